// Round 1
// baseline (681.690 us; speedup 1.0000x reference)
//
#include <hip/hip_runtime.h>
#include <math.h>

#define DD 1024
#define HH1 4096
#define HH2 4096

// ws layout (floats): [0) u0 | [4096) q | [8192) s | [12288) cv  — 64 KB total

__device__ inline void wave_reduce2(float& a, float& b) {
  #pragma unroll
  for (int off = 32; off > 0; off >>= 1) {
    a += __shfl_down(a, off, 64);
    b += __shfl_down(b, off, 64);
  }
}

// K1: per-row h of W1: a0=W1[h,:]·x+b1, r=Σ W1[h,i]^2 → u0,s,q. Also zeroes out.
__global__ __launch_bounds__(256) void k1_layer1(
    const float* __restrict__ W1, const float* __restrict__ x,
    const float* __restrict__ b1, float* __restrict__ u0,
    float* __restrict__ q, float* __restrict__ s_out,
    float* __restrict__ out) {
  int h = blockIdx.x;
  int tid = threadIdx.x;
  const float4* row = (const float4*)(W1 + (size_t)h * DD);
  const float4* x4 = (const float4*)x;
  float4 w = row[tid];
  float4 xv = x4[tid];
  float dot = w.x * xv.x + w.y * xv.y + w.z * xv.z + w.w * xv.w;
  float sq = w.x * w.x + w.y * w.y + w.z * w.z + w.w * w.w;
  wave_reduce2(dot, sq);
  __shared__ float lds[8];
  int lane = tid & 63, wid = tid >> 6;
  if (lane == 0) { lds[wid * 2] = dot; lds[wid * 2 + 1] = sq; }
  __syncthreads();
  if (tid == 0) {
    float dsum = lds[0] + lds[2] + lds[4] + lds[6];
    float rsum = lds[1] + lds[3] + lds[5] + lds[7];
    float a0 = dsum + b1[h];
    float u = tanhf(a0);
    float s = 1.f - u * u;
    u0[h] = u;
    s_out[h] = s;
    q[h] = -2.f * u * s * rsum;
    if (h == 0) out[0] = 0.f;  // harness re-poisons d_out; we own the zero-init
  }
}

// K2: per-row g of W2: z=W2[g,:]·u0+b2, d=W2[g,:]·q → cv[g]=c*v0, out += c*d
__global__ __launch_bounds__(256) void k2_layer2(
    const float* __restrict__ W2, const float* __restrict__ b2,
    const float* __restrict__ W3, const float* __restrict__ u0,
    const float* __restrict__ q, float* __restrict__ cv,
    float* __restrict__ out) {
  int g = blockIdx.x;
  int tid = threadIdx.x;
  const float4* row = (const float4*)(W2 + (size_t)g * HH1);
  const float4* u4 = (const float4*)u0;
  const float4* q4 = (const float4*)q;
  float zacc = 0.f, dacc = 0.f;
  for (int j = tid; j < HH1 / 4; j += 256) {
    float4 w = row[j];
    float4 u = u4[j];
    float4 qq = q4[j];
    zacc += w.x * u.x + w.y * u.y + w.z * u.z + w.w * u.w;
    dacc += w.x * qq.x + w.y * qq.y + w.z * qq.z + w.w * qq.w;
  }
  wave_reduce2(zacc, dacc);
  __shared__ float lds[8];
  int lane = tid & 63, wid = tid >> 6;
  if (lane == 0) { lds[wid * 2] = zacc; lds[wid * 2 + 1] = dacc; }
  __syncthreads();
  if (tid == 0) {
    float z = lds[0] + lds[2] + lds[4] + lds[6] + b2[g];
    float d = lds[1] + lds[3] + lds[5] + lds[7];
    float v = tanhf(z);
    float t = 1.f - v * v;
    float c = W3[g] * t;
    cv[g] = c * v;
    atomicAdd(out, c * d);
  }
}

// K4: GEMM M = (W2⊙s)·W1, tile 64x64, BK=32; reduce cv[g]*Σ M[g,i]^2 per block,
// single atomicAdd of -2*partial into out. M never hits global memory.
#define BM 64
#define BN 64
#define BK 32

__global__ __launch_bounds__(256) void k4_rownorm(
    const float* __restrict__ W2, const float* __restrict__ W1,
    const float* __restrict__ s, const float* __restrict__ cv,
    float* __restrict__ out) {
  __shared__ float As[BK][BM + 4];  // transposed: As[k][m]; +4 pad keeps f4 align
  __shared__ float Bs[BK][BN + 4];
  int tid = threadIdx.x;
  int g0 = blockIdx.y * BM;
  int i0 = blockIdx.x * BN;
  int tr = (tid / 16) * 4;
  int tc = (tid % 16) * 4;
  float acc[4][4] = {};
  for (int k0 = 0; k0 < HH1; k0 += BK) {
    // A tile: 64 rows (g) x 32 cols (h) of W2, scaled by s[h], stored transposed
    for (int l = tid; l < (BM * BK / 4); l += 256) {
      int row = l / (BK / 4);
      int c4 = l % (BK / 4);
      float4 w = *(const float4*)(W2 + (size_t)(g0 + row) * HH1 + k0 + c4 * 4);
      float4 sv = *(const float4*)(s + k0 + c4 * 4);
      As[c4 * 4 + 0][row] = w.x * sv.x;
      As[c4 * 4 + 1][row] = w.y * sv.y;
      As[c4 * 4 + 2][row] = w.z * sv.z;
      As[c4 * 4 + 3][row] = w.w * sv.w;
    }
    // B tile: 32 rows (h) x 64 cols (i) of W1
    for (int l = tid; l < (BK * BN / 4); l += 256) {
      int row = l / (BN / 4);
      int c4 = l % (BN / 4);
      float4 w = *(const float4*)(W1 + (size_t)(k0 + row) * DD + i0 + c4 * 4);
      *(float4*)&Bs[row][c4 * 4] = w;
    }
    __syncthreads();
    #pragma unroll
    for (int k = 0; k < BK; ++k) {
      float4 av = *(const float4*)&As[k][tr];
      float4 bv = *(const float4*)&Bs[k][tc];
      float a_[4] = {av.x, av.y, av.z, av.w};
      float b_[4] = {bv.x, bv.y, bv.z, bv.w};
      #pragma unroll
      for (int r = 0; r < 4; ++r)
        #pragma unroll
        for (int c = 0; c < 4; ++c)
          acc[r][c] += a_[r] * b_[c];
    }
    __syncthreads();
  }
  float contrib = 0.f;
  #pragma unroll
  for (int r = 0; r < 4; ++r) {
    float ss = acc[r][0] * acc[r][0] + acc[r][1] * acc[r][1] +
               acc[r][2] * acc[r][2] + acc[r][3] * acc[r][3];
    contrib += cv[g0 + tr + r] * ss;
  }
  #pragma unroll
  for (int off = 32; off > 0; off >>= 1) contrib += __shfl_down(contrib, off, 64);
  __shared__ float red[4];
  int lane = tid & 63, wid = tid >> 6;
  if (lane == 0) red[wid] = contrib;
  __syncthreads();
  if (tid == 0) atomicAdd(out, -2.f * (red[0] + red[1] + red[2] + red[3]));
}

extern "C" void kernel_launch(void* const* d_in, const int* in_sizes, int n_in,
                              void* d_out, int out_size, void* d_ws, size_t ws_size,
                              hipStream_t stream) {
  const float* x  = (const float*)d_in[0];
  const float* W1 = (const float*)d_in[1];
  const float* b1 = (const float*)d_in[2];
  const float* W2 = (const float*)d_in[3];
  const float* b2 = (const float*)d_in[4];
  const float* W3 = (const float*)d_in[5];
  // b3 (d_in[6]) is a constant offset — vanishes under the Laplacian.
  float* out = (float*)d_out;
  float* ws = (float*)d_ws;
  float* u0 = ws;
  float* q  = ws + 4096;
  float* s  = ws + 8192;
  float* cv = ws + 12288;

  hipLaunchKernelGGL(k1_layer1, dim3(HH1), dim3(256), 0, stream, W1, x, b1, u0, q, s, out);
  hipLaunchKernelGGL(k2_layer2, dim3(HH2), dim3(256), 0, stream, W2, b2, W3, u0, q, cv, out);
  hipLaunchKernelGGL(k4_rownorm, dim3(DD / BN, HH2 / BM), dim3(256), 0, stream,
                     W2, W1, s, cv, out);
}

// Round 2
// 300.809 us; speedup vs baseline: 2.2662x; 2.2662x over previous
//
#include <hip/hip_runtime.h>
#include <math.h>

#define DD 1024
#define HH1 4096
#define HH2 4096

typedef __attribute__((ext_vector_type(8))) short bf16x8;
typedef __attribute__((ext_vector_type(4))) float f32x4;

// ws layout (floats): [0) u0 | [4096) q | [8192) s | [12288) cv

__device__ inline void wave_reduce2(float& a, float& b) {
  #pragma unroll
  for (int off = 32; off > 0; off >>= 1) {
    a += __shfl_down(a, off, 64);
    b += __shfl_down(b, off, 64);
  }
}

// fp32 -> bf16 with round-to-nearest-even (pure bit ops; no header deps)
__device__ inline unsigned int f2b(float f) {
  union { float f; unsigned int u; } v; v.f = f;
  return (v.u + 0x7FFFu + ((v.u >> 16) & 1u)) >> 16;
}
__device__ inline unsigned int pack2(float a, float b) {
  return f2b(a) | (f2b(b) << 16);
}

// K1: per-row h of W1: a0=W1[h,:]·x+b1, r=Σ W1[h,i]^2 → u0,s,q. Also zeroes out.
__global__ __launch_bounds__(256) void k1_layer1(
    const float* __restrict__ W1, const float* __restrict__ x,
    const float* __restrict__ b1, float* __restrict__ u0,
    float* __restrict__ q, float* __restrict__ s_out,
    float* __restrict__ out) {
  int h = blockIdx.x;
  int tid = threadIdx.x;
  const float4* row = (const float4*)(W1 + (size_t)h * DD);
  const float4* x4 = (const float4*)x;
  float4 w = row[tid];
  float4 xv = x4[tid];
  float dot = w.x * xv.x + w.y * xv.y + w.z * xv.z + w.w * xv.w;
  float sq = w.x * w.x + w.y * w.y + w.z * w.z + w.w * w.w;
  wave_reduce2(dot, sq);
  __shared__ float lds[8];
  int lane = tid & 63, wid = tid >> 6;
  if (lane == 0) { lds[wid * 2] = dot; lds[wid * 2 + 1] = sq; }
  __syncthreads();
  if (tid == 0) {
    float dsum = lds[0] + lds[2] + lds[4] + lds[6];
    float rsum = lds[1] + lds[3] + lds[5] + lds[7];
    float a0 = dsum + b1[h];
    float u = tanhf(a0);
    float s = 1.f - u * u;
    u0[h] = u;
    s_out[h] = s;
    q[h] = -2.f * u * s * rsum;
    if (h == 0) out[0] = 0.f;
  }
}

// K2: per-row g of W2: z=W2[g,:]·u0+b2, d=W2[g,:]·q → cv[g]=c*v0, out += c*d
__global__ __launch_bounds__(256) void k2_layer2(
    const float* __restrict__ W2, const float* __restrict__ b2,
    const float* __restrict__ W3, const float* __restrict__ u0,
    const float* __restrict__ q, float* __restrict__ cv,
    float* __restrict__ out) {
  int g = blockIdx.x;
  int tid = threadIdx.x;
  const float4* row = (const float4*)(W2 + (size_t)g * HH1);
  const float4* u4 = (const float4*)u0;
  const float4* q4 = (const float4*)q;
  float zacc = 0.f, dacc = 0.f;
  for (int j = tid; j < HH1 / 4; j += 256) {
    float4 w = row[j];
    float4 u = u4[j];
    float4 qq = q4[j];
    zacc += w.x * u.x + w.y * u.y + w.z * u.z + w.w * u.w;
    dacc += w.x * qq.x + w.y * qq.y + w.z * qq.z + w.w * qq.w;
  }
  wave_reduce2(zacc, dacc);
  __shared__ float lds[8];
  int lane = tid & 63, wid = tid >> 6;
  if (lane == 0) { lds[wid * 2] = zacc; lds[wid * 2 + 1] = dacc; }
  __syncthreads();
  if (tid == 0) {
    float z = lds[0] + lds[2] + lds[4] + lds[6] + b2[g];
    float d = lds[1] + lds[3] + lds[5] + lds[7];
    float v = tanhf(z);
    float t = 1.f - v * v;
    float c = W3[g] * t;
    cv[g] = c * v;
    atomicAdd(out, c * d);
  }
}

// K4: bf16 MFMA GEMM M = (W2⊙s)·W1, tile 128x128, BK=32, double-buffered LDS.
// Per-element square+cv-weighted reduce in the epilogue; single atomic per block.
// A in LDS: padded [128][40] rows (80 B stride, ~2-way banks for b128 frag reads).
// B in LDS: unpadded [128][32] with XOR swizzle of 4-B k-pair granules:
//   phys granule = q ^ ((n>>2)&15)  → scatter writes 2-way (free), frag reads 4x b32.
__global__ __launch_bounds__(256) void k4_mfma(
    const float* __restrict__ W2, const float* __restrict__ W1,
    const float* __restrict__ s, const float* __restrict__ cv,
    float* __restrict__ out) {
  __shared__ __align__(16) unsigned short As[2][128][40];
  __shared__ __align__(16) unsigned short Bs[2][128][32];
  __shared__ float red[4];

  const int tid = threadIdx.x;
  const int lane = tid & 63;
  const int wave = tid >> 6;
  const int wm = wave >> 1, wn = wave & 1;
  const int g0 = blockIdx.y * 128;
  const int i0 = blockIdx.x * 128;

  // staging index maps
  const int a_row = tid >> 3;          // 0..31 (+32 per pass)
  const int a_k = (tid & 7) * 4;       // k offset {0,4,...,28}
  const int b_n4 = (tid & 31) * 4;     // n offset {0,4,...,124}
  const int b_kp = tid >> 5;           // k-pair 0..7 (+8 on 2nd pass)

  float4 pa[4];
  float4 ps;
  float4 pb[2][2];  // [pass][row of k-pair]

  auto load_tile = [&](int k0) {
    #pragma unroll
    for (int p = 0; p < 4; ++p)
      pa[p] = *(const float4*)(W2 + (size_t)(g0 + p * 32 + a_row) * HH1 + k0 + a_k);
    ps = *(const float4*)(s + k0 + a_k);
    #pragma unroll
    for (int pp = 0; pp < 2; ++pp) {
      int k = k0 + (pp * 8 + b_kp) * 2;
      pb[pp][0] = *(const float4*)(W1 + (size_t)k * DD + i0 + b_n4);
      pb[pp][1] = *(const float4*)(W1 + (size_t)(k + 1) * DD + i0 + b_n4);
    }
  };

  auto store_tile = [&](int buf) {
    #pragma unroll
    for (int p = 0; p < 4; ++p) {
      uint2 v;
      v.x = pack2(pa[p].x * ps.x, pa[p].y * ps.y);
      v.y = pack2(pa[p].z * ps.z, pa[p].w * ps.w);
      *(uint2*)&As[buf][p * 32 + a_row][a_k] = v;
    }
    #pragma unroll
    for (int pp = 0; pp < 2; ++pp) {
      int q = pp * 8 + b_kp;  // k-pair index 0..15
      const float* r0 = (const float*)&pb[pp][0];
      const float* r1 = (const float*)&pb[pp][1];
      #pragma unroll
      for (int c = 0; c < 4; ++c) {
        int n = b_n4 + c;
        int qp = q ^ ((n >> 2) & 15);
        *(unsigned int*)&Bs[buf][n][qp * 2] = pack2(r0[c], r1[c]);
      }
    }
  };

  f32x4 acc[4][4];
  const f32x4 zero = {0.f, 0.f, 0.f, 0.f};
  #pragma unroll
  for (int mt = 0; mt < 4; ++mt)
    #pragma unroll
    for (int nt = 0; nt < 4; ++nt) acc[mt][nt] = zero;

  const int fr = lane & 15;
  const int fc = lane >> 4;  // k-chunk 0..3

  auto mfma_phase = [&](int buf) {
    bf16x8 af[4], bfr[4];
    #pragma unroll
    for (int mt = 0; mt < 4; ++mt)
      af[mt] = *(const bf16x8*)&As[buf][wm * 64 + mt * 16 + fr][fc * 8];
    #pragma unroll
    for (int nt = 0; nt < 4; ++nt) {
      int n = wn * 64 + nt * 16 + fr;
      int sw = (n >> 2) & 15;
      union { bf16x8 v; unsigned int u[4]; } bu;
      #pragma unroll
      for (int j = 0; j < 4; ++j) {
        int q = fc * 4 + j;
        bu.u[j] = *(const unsigned int*)&Bs[buf][n][(q ^ sw) * 2];
      }
      bfr[nt] = bu.v;
    }
    #pragma unroll
    for (int mt = 0; mt < 4; ++mt)
      #pragma unroll
      for (int nt = 0; nt < 4; ++nt)
        acc[mt][nt] = __builtin_amdgcn_mfma_f32_16x16x32_bf16(
            af[mt], bfr[nt], acc[mt][nt], 0, 0, 0);
  };

  load_tile(0);
  store_tile(0);
  __syncthreads();
  for (int ko = 0; ko < HH1 / 32; ++ko) {
    int cur = ko & 1;
    if (ko + 1 < HH1 / 32) load_tile((ko + 1) * 32);
    mfma_phase(cur);
    if (ko + 1 < HH1 / 32) {
      store_tile(cur ^ 1);
      __syncthreads();
    }
  }

  // epilogue: out += -2 * Σ cv[g] * M[g,i]^2 over this block's tile
  float part = 0.f;
  #pragma unroll
  for (int mt = 0; mt < 4; ++mt) {
    #pragma unroll
    for (int r = 0; r < 4; ++r) {
      int g = g0 + wm * 64 + mt * 16 + fc * 4 + r;
      float c = cv[g];
      float ss = 0.f;
      #pragma unroll
      for (int nt = 0; nt < 4; ++nt) {
        float v = acc[mt][nt][r];
        ss += v * v;
      }
      part += c * ss;
    }
  }
  #pragma unroll
  for (int off = 32; off > 0; off >>= 1) part += __shfl_down(part, off, 64);
  if (lane == 0) red[wave] = part;
  __syncthreads();
  if (tid == 0) atomicAdd(out, -2.f * (red[0] + red[1] + red[2] + red[3]));
}

extern "C" void kernel_launch(void* const* d_in, const int* in_sizes, int n_in,
                              void* d_out, int out_size, void* d_ws, size_t ws_size,
                              hipStream_t stream) {
  const float* x  = (const float*)d_in[0];
  const float* W1 = (const float*)d_in[1];
  const float* b1 = (const float*)d_in[2];
  const float* W2 = (const float*)d_in[3];
  const float* b2 = (const float*)d_in[4];
  const float* W3 = (const float*)d_in[5];
  // b3 (d_in[6]) is a constant offset — vanishes under the Laplacian.
  float* out = (float*)d_out;
  float* ws = (float*)d_ws;
  float* u0 = ws;
  float* q  = ws + 4096;
  float* s  = ws + 8192;
  float* cv = ws + 12288;

  hipLaunchKernelGGL(k1_layer1, dim3(HH1), dim3(256), 0, stream, W1, x, b1, u0, q, s, out);
  hipLaunchKernelGGL(k2_layer2, dim3(HH2), dim3(256), 0, stream, W2, b2, W3, u0, q, cv, out);
  hipLaunchKernelGGL(k4_mfma, dim3(DD / 128, HH2 / 128), dim3(256), 0, stream,
                     W2, W1, s, cv, out);
}

// Round 3
// 229.205 us; speedup vs baseline: 2.9742x; 1.3124x over previous
//
#include <hip/hip_runtime.h>
#include <math.h>

#define DD 1024
#define HH1 4096
#define HH2 4096

typedef __attribute__((ext_vector_type(8))) short bf16x8;
typedef __attribute__((ext_vector_type(4))) float f32x4;
typedef unsigned short ushort_t;

// fast-path ws layout (bytes):
//   [0)        u0 (4096 f32)
//   [16384)    q  (4096 f32)
//   [32768)    s  (4096 f32)
//   [49152)    cv (4096 f32)
//   [65536)    A' = bf16(W2 .* s)   4096x4096  (33554432 B)
//   [33619968) B' = bf16(W1^T)      1024x4096  ( 8388608 B)
#define WS_FAST_BYTES 42008576ull

__device__ inline void wave_reduce2(float& a, float& b) {
  #pragma unroll
  for (int off = 32; off > 0; off >>= 1) {
    a += __shfl_down(a, off, 64);
    b += __shfl_down(b, off, 64);
  }
}

// fp32 -> bf16 RNE
__device__ inline unsigned int f2b(float f) {
  union { float f; unsigned int u; } v; v.f = f;
  return (v.u + 0x7FFFu + ((v.u >> 16) & 1u)) >> 16;
}
__device__ inline unsigned int pack2(float a, float b) {
  return f2b(a) | (f2b(b) << 16);
}

// async global->LDS, 16 B per lane; LDS dst is wave-uniform base + lane*16
__device__ inline void gl_lds16(const void* g, void* l) {
  __builtin_amdgcn_global_load_lds(
      (const __attribute__((address_space(1))) unsigned int*)g,
      (__attribute__((address_space(3))) unsigned int*)l, 16, 0, 0);
}

// K1: per-row h of W1: a0=W1[h,:]·x+b1, r=Σ W1[h,i]^2 → u0,s,q. Zeroes out.
__global__ __launch_bounds__(256) void k1_layer1(
    const float* __restrict__ W1, const float* __restrict__ x,
    const float* __restrict__ b1, float* __restrict__ u0,
    float* __restrict__ q, float* __restrict__ s_out,
    float* __restrict__ out) {
  int h = blockIdx.x;
  int tid = threadIdx.x;
  const float4* row = (const float4*)(W1 + (size_t)h * DD);
  const float4* x4 = (const float4*)x;
  float4 w = row[tid];
  float4 xv = x4[tid];
  float dot = w.x * xv.x + w.y * xv.y + w.z * xv.z + w.w * xv.w;
  float sq = w.x * w.x + w.y * w.y + w.z * w.z + w.w * w.w;
  wave_reduce2(dot, sq);
  __shared__ float lds[8];
  int lane = tid & 63, wid = tid >> 6;
  if (lane == 0) { lds[wid * 2] = dot; lds[wid * 2 + 1] = sq; }
  __syncthreads();
  if (tid == 0) {
    float dsum = lds[0] + lds[2] + lds[4] + lds[6];
    float rsum = lds[1] + lds[3] + lds[5] + lds[7];
    float a0 = dsum + b1[h];
    float u = tanhf(a0);
    float s = 1.f - u * u;
    u0[h] = u;
    s_out[h] = s;
    q[h] = -2.f * u * s * rsum;
    if (h == 0) out[0] = 0.f;
  }
}

// K0b: transpose-convert W1 [4096 k][1024 i] fp32 -> B' [1024 i][4096 k] bf16.
__global__ __launch_bounds__(256) void k0b_transpose(
    const float* __restrict__ W1, ushort_t* __restrict__ Bp) {
  __shared__ ushort_t T[64][72];  // stride 72 (144 B = 9*16) keeps 16B-aligned rows
  int tid = threadIdx.x;
  int k0 = blockIdx.x * 64;
  int i0 = blockIdx.y * 64;
  int kr = tid >> 4;          // 0..15
  int ic = (tid & 15) * 4;    // 0..60
  #pragma unroll
  for (int p = 0; p < 4; ++p) {
    int k = kr + p * 16;
    float4 v = *(const float4*)(W1 + (size_t)(k0 + k) * DD + i0 + ic);
    T[ic + 0][k] = (ushort_t)f2b(v.x);
    T[ic + 1][k] = (ushort_t)f2b(v.y);
    T[ic + 2][k] = (ushort_t)f2b(v.z);
    T[ic + 3][k] = (ushort_t)f2b(v.w);
  }
  __syncthreads();
  int kc = tid & 7;           // 8 chunks of 8 k (16 B)
  int ir = tid >> 3;          // 0..31
  #pragma unroll
  for (int p = 0; p < 2; ++p) {
    int i = ir + p * 32;
    uint4 v = *(const uint4*)&T[i][kc * 8];
    *(uint4*)(Bp + (size_t)(i0 + i) * HH1 + k0 + kc * 8) = v;
  }
}

// K0a: per-row g of W2 (fused old k2): z=W2[g,:]·u0+b2, d=W2[g,:]·q,
// write A'[g,:] = bf16(W2[g,:] .* s); cv[g]=c*v0; out += c*d.
__global__ __launch_bounds__(256) void k0a_layer2conv(
    const float* __restrict__ W2, const float* __restrict__ b2,
    const float* __restrict__ W3, const float* __restrict__ u0,
    const float* __restrict__ q, const float* __restrict__ s,
    ushort_t* __restrict__ Ap, float* __restrict__ cv,
    float* __restrict__ out) {
  int g = blockIdx.x;
  int tid = threadIdx.x;
  const float4* row = (const float4*)(W2 + (size_t)g * HH1);
  const float4* u4 = (const float4*)u0;
  const float4* q4 = (const float4*)q;
  const float4* s4 = (const float4*)s;
  float zacc = 0.f, dacc = 0.f;
  #pragma unroll
  for (int it = 0; it < 4; ++it) {
    int j = tid + it * 256;  // j < 1024
    float4 w = row[j];
    float4 u = u4[j];
    float4 qq = q4[j];
    float4 sv = s4[j];
    zacc += w.x * u.x + w.y * u.y + w.z * u.z + w.w * u.w;
    dacc += w.x * qq.x + w.y * qq.y + w.z * qq.z + w.w * qq.w;
    uint2 pk;
    pk.x = pack2(w.x * sv.x, w.y * sv.y);
    pk.y = pack2(w.z * sv.z, w.w * sv.w);
    *(uint2*)(Ap + (size_t)g * HH1 + j * 4) = pk;
  }
  wave_reduce2(zacc, dacc);
  __shared__ float lds[8];
  int lane = tid & 63, wid = tid >> 6;
  if (lane == 0) { lds[wid * 2] = zacc; lds[wid * 2 + 1] = dacc; }
  __syncthreads();
  if (tid == 0) {
    float z = lds[0] + lds[2] + lds[4] + lds[6] + b2[g];
    float d = lds[1] + lds[3] + lds[5] + lds[7];
    float v = tanhf(z);
    float t = 1.f - v * v;
    float c = W3[g] * t;
    cv[g] = c * v;
    atomicAdd(out, c * d);
  }
}

// K4 fast: bf16 GEMM-BT M = A' · B'^T, tile 128(m=g) x 64(n=i), BK=32,
// m97-style: global_load_lds 16B staging, single LDS buffer, 2 barriers/iter.
// k-chunk placement XOR-swizzled (chunk ^ ((row>>1)&3)) -> 2-way banks (free).
// Epilogue: out += -2 * Σ cv[g] * M[g,i]^2 ; one atomic per block.
__global__ __launch_bounds__(256) void k4_bt(
    const ushort_t* __restrict__ Ap, const ushort_t* __restrict__ Bp,
    const float* __restrict__ cv, float* __restrict__ out) {
  __shared__ __align__(16) ushort_t As[128][32];
  __shared__ __align__(16) ushort_t Bs[64][32];
  __shared__ float red[4];
  const int tid = threadIdx.x;
  const int lane = tid & 63;
  const int wave = tid >> 6;
  const int wm = wave >> 1, wn = wave & 1;
  // XCD swizzle: XCD c owns g-stripes {4c..4c+3} x all i  (per-XCD fills ~12 MB)
  const int l = blockIdx.x;
  const int xcd = l & 7, j = l >> 3;
  const int g0 = (xcd * 4 + (j & 3)) * 128;
  const int i0 = (j >> 2) * 64;

  const int sr = lane >> 2;      // row within a 16-row staging group
  const int pchunk = lane & 3;   // physical 16B chunk this lane fills

  f32x4 acc[4][2];
  const f32x4 zero = {0.f, 0.f, 0.f, 0.f};
  #pragma unroll
  for (int mt = 0; mt < 4; ++mt)
    #pragma unroll
    for (int nt = 0; nt < 2; ++nt) acc[mt][nt] = zero;

  const int fr = lane & 15;
  const int fc = lane >> 4;

  for (int ko = 0; ko < HH1 / 32; ++ko) {
    const int k0 = ko * 32;
    // stage A: wave w covers rows [w*32, w*32+32)
    #pragma unroll
    for (int p = 0; p < 2; ++p) {
      int row0 = wave * 32 + p * 16;
      int r = row0 + sr;
      int kc = pchunk ^ ((r >> 1) & 3);
      gl_lds16(Ap + (size_t)(g0 + r) * HH1 + k0 + kc * 8,
               (char*)&As[0][0] + row0 * 64 + lane * 16);
    }
    // stage B: wave w covers rows [w*16, w*16+16)
    {
      int row0 = wave * 16;
      int r = row0 + sr;
      int kc = pchunk ^ ((r >> 1) & 3);
      gl_lds16(Bp + (size_t)(i0 + r) * HH1 + k0 + kc * 8,
               (char*)&Bs[0][0] + row0 * 64 + lane * 16);
    }
    __syncthreads();  // drains vmcnt (global_load_lds) per m97 semantics
    bf16x8 af[4], bf[2];
    #pragma unroll
    for (int mt = 0; mt < 4; ++mt) {
      int row = wm * 64 + mt * 16 + fr;
      af[mt] = *(const bf16x8*)&As[row][(fc ^ ((row >> 1) & 3)) * 8];
    }
    #pragma unroll
    for (int nt = 0; nt < 2; ++nt) {
      int row = wn * 32 + nt * 16 + fr;
      bf[nt] = *(const bf16x8*)&Bs[row][(fc ^ ((row >> 1) & 3)) * 8];
    }
    #pragma unroll
    for (int mt = 0; mt < 4; ++mt)
      #pragma unroll
      for (int nt = 0; nt < 2; ++nt)
        acc[mt][nt] = __builtin_amdgcn_mfma_f32_16x16x32_bf16(
            af[mt], bf[nt], acc[mt][nt], 0, 0, 0);
    __syncthreads();
  }

  float part = 0.f;
  #pragma unroll
  for (int mt = 0; mt < 4; ++mt) {
    #pragma unroll
    for (int r = 0; r < 4; ++r) {
      int g = g0 + wm * 64 + mt * 16 + fc * 4 + r;
      float c = cv[g];
      float ss = 0.f;
      #pragma unroll
      for (int nt = 0; nt < 2; ++nt) {
        float v = acc[mt][nt][r];
        ss += v * v;
      }
      part += c * ss;
    }
  }
  #pragma unroll
  for (int off = 32; off > 0; off >>= 1) part += __shfl_down(part, off, 64);
  if (lane == 0) red[wave] = part;
  __syncthreads();
  if (tid == 0) atomicAdd(out, -2.f * (red[0] + red[1] + red[2] + red[3]));
}

// ---------------- fallback path (R2 kernels, used when ws is too small) ------

__global__ __launch_bounds__(256) void k2_layer2(
    const float* __restrict__ W2, const float* __restrict__ b2,
    const float* __restrict__ W3, const float* __restrict__ u0,
    const float* __restrict__ q, float* __restrict__ cv,
    float* __restrict__ out) {
  int g = blockIdx.x;
  int tid = threadIdx.x;
  const float4* row = (const float4*)(W2 + (size_t)g * HH1);
  const float4* u4 = (const float4*)u0;
  const float4* q4 = (const float4*)q;
  float zacc = 0.f, dacc = 0.f;
  for (int j = tid; j < HH1 / 4; j += 256) {
    float4 w = row[j];
    float4 u = u4[j];
    float4 qq = q4[j];
    zacc += w.x * u.x + w.y * u.y + w.z * u.z + w.w * u.w;
    dacc += w.x * qq.x + w.y * qq.y + w.z * qq.z + w.w * qq.w;
  }
  wave_reduce2(zacc, dacc);
  __shared__ float lds[8];
  int lane = tid & 63, wid = tid >> 6;
  if (lane == 0) { lds[wid * 2] = zacc; lds[wid * 2 + 1] = dacc; }
  __syncthreads();
  if (tid == 0) {
    float z = lds[0] + lds[2] + lds[4] + lds[6] + b2[g];
    float d = lds[1] + lds[3] + lds[5] + lds[7];
    float v = tanhf(z);
    float t = 1.f - v * v;
    float c = W3[g] * t;
    cv[g] = c * v;
    atomicAdd(out, c * d);
  }
}

__global__ __launch_bounds__(256) void k4_mfma(
    const float* __restrict__ W2, const float* __restrict__ W1,
    const float* __restrict__ s, const float* __restrict__ cv,
    float* __restrict__ out) {
  __shared__ __align__(16) unsigned short As[2][128][40];
  __shared__ __align__(16) unsigned short Bs[2][128][32];
  __shared__ float red[4];
  const int tid = threadIdx.x;
  const int lane = tid & 63;
  const int wave = tid >> 6;
  const int wm = wave >> 1, wn = wave & 1;
  const int g0 = blockIdx.y * 128;
  const int i0 = blockIdx.x * 128;
  const int a_row = tid >> 3;
  const int a_k = (tid & 7) * 4;
  const int b_n4 = (tid & 31) * 4;
  const int b_kp = tid >> 5;
  float4 pa[4];
  float4 ps;
  float4 pb[2][2];
  auto load_tile = [&](int k0) {
    #pragma unroll
    for (int p = 0; p < 4; ++p)
      pa[p] = *(const float4*)(W2 + (size_t)(g0 + p * 32 + a_row) * HH1 + k0 + a_k);
    ps = *(const float4*)(s + k0 + a_k);
    #pragma unroll
    for (int pp = 0; pp < 2; ++pp) {
      int k = k0 + (pp * 8 + b_kp) * 2;
      pb[pp][0] = *(const float4*)(W1 + (size_t)k * DD + i0 + b_n4);
      pb[pp][1] = *(const float4*)(W1 + (size_t)(k + 1) * DD + i0 + b_n4);
    }
  };
  auto store_tile = [&](int buf) {
    #pragma unroll
    for (int p = 0; p < 4; ++p) {
      uint2 v;
      v.x = pack2(pa[p].x * ps.x, pa[p].y * ps.y);
      v.y = pack2(pa[p].z * ps.z, pa[p].w * ps.w);
      *(uint2*)&As[buf][p * 32 + a_row][a_k] = v;
    }
    #pragma unroll
    for (int pp = 0; pp < 2; ++pp) {
      int q = pp * 8 + b_kp;
      const float* r0 = (const float*)&pb[pp][0];
      const float* r1 = (const float*)&pb[pp][1];
      #pragma unroll
      for (int c = 0; c < 4; ++c) {
        int n = b_n4 + c;
        int qp = q ^ ((n >> 2) & 15);
        *(unsigned int*)&Bs[buf][n][qp * 2] = pack2(r0[c], r1[c]);
      }
    }
  };
  f32x4 acc[4][4];
  const f32x4 zero = {0.f, 0.f, 0.f, 0.f};
  #pragma unroll
  for (int mt = 0; mt < 4; ++mt)
    #pragma unroll
    for (int nt = 0; nt < 4; ++nt) acc[mt][nt] = zero;
  const int fr = lane & 15;
  const int fc = lane >> 4;
  auto mfma_phase = [&](int buf) {
    bf16x8 af[4], bfr[4];
    #pragma unroll
    for (int mt = 0; mt < 4; ++mt)
      af[mt] = *(const bf16x8*)&As[buf][wm * 64 + mt * 16 + fr][fc * 8];
    #pragma unroll
    for (int nt = 0; nt < 4; ++nt) {
      int n = wn * 64 + nt * 16 + fr;
      int sw = (n >> 2) & 15;
      union { bf16x8 v; unsigned int u[4]; } bu;
      #pragma unroll
      for (int jj = 0; jj < 4; ++jj) {
        int qq = fc * 4 + jj;
        bu.u[jj] = *(const unsigned int*)&Bs[buf][n][(qq ^ sw) * 2];
      }
      bfr[nt] = bu.v;
    }
    #pragma unroll
    for (int mt = 0; mt < 4; ++mt)
      #pragma unroll
      for (int nt = 0; nt < 4; ++nt)
        acc[mt][nt] = __builtin_amdgcn_mfma_f32_16x16x32_bf16(
            af[mt], bfr[nt], acc[mt][nt], 0, 0, 0);
  };
  load_tile(0);
  store_tile(0);
  __syncthreads();
  for (int ko = 0; ko < HH1 / 32; ++ko) {
    int cur = ko & 1;
    if (ko + 1 < HH1 / 32) load_tile((ko + 1) * 32);
    mfma_phase(cur);
    if (ko + 1 < HH1 / 32) {
      store_tile(cur ^ 1);
      __syncthreads();
    }
  }
  float part = 0.f;
  #pragma unroll
  for (int mt = 0; mt < 4; ++mt) {
    #pragma unroll
    for (int r = 0; r < 4; ++r) {
      int g = g0 + wm * 64 + mt * 16 + fc * 4 + r;
      float c = cv[g];
      float ss = 0.f;
      #pragma unroll
      for (int nt = 0; nt < 4; ++nt) {
        float v = acc[mt][nt][r];
        ss += v * v;
      }
      part += c * ss;
    }
  }
  #pragma unroll
  for (int off = 32; off > 0; off >>= 1) part += __shfl_down(part, off, 64);
  if (lane == 0) red[wave] = part;
  __syncthreads();
  if (tid == 0) atomicAdd(out, -2.f * (red[0] + red[1] + red[2] + red[3]));
}

extern "C" void kernel_launch(void* const* d_in, const int* in_sizes, int n_in,
                              void* d_out, int out_size, void* d_ws, size_t ws_size,
                              hipStream_t stream) {
  const float* x  = (const float*)d_in[0];
  const float* W1 = (const float*)d_in[1];
  const float* b1 = (const float*)d_in[2];
  const float* W2 = (const float*)d_in[3];
  const float* b2 = (const float*)d_in[4];
  const float* W3 = (const float*)d_in[5];
  float* out = (float*)d_out;
  float* ws = (float*)d_ws;
  float* u0 = ws;
  float* q  = ws + 4096;
  float* s  = ws + 8192;
  float* cv = ws + 12288;

  hipLaunchKernelGGL(k1_layer1, dim3(HH1), dim3(256), 0, stream, W1, x, b1, u0, q, s, out);

  if (ws_size >= WS_FAST_BYTES) {
    ushort_t* Ap = (ushort_t*)((char*)d_ws + 65536);
    ushort_t* Bp = (ushort_t*)((char*)d_ws + 33619968);
    hipLaunchKernelGGL(k0b_transpose, dim3(64, 16), dim3(256), 0, stream, W1, Bp);
    hipLaunchKernelGGL(k0a_layer2conv, dim3(HH2), dim3(256), 0, stream,
                       W2, b2, W3, u0, q, s, Ap, cv, out);
    hipLaunchKernelGGL(k4_bt, dim3(512), dim3(256), 0, stream, Ap, Bp, cv, out);
  } else {
    hipLaunchKernelGGL(k2_layer2, dim3(HH2), dim3(256), 0, stream, W2, b2, W3, u0, q, cv, out);
    hipLaunchKernelGGL(k4_mfma, dim3(DD / 128, HH2 / 128), dim3(256), 0, stream,
                       W2, W1, s, cv, out);
  }
}

// Round 4
// 193.068 us; speedup vs baseline: 3.5308x; 1.1872x over previous
//
#include <hip/hip_runtime.h>
#include <math.h>

#define DD 1024
#define HH1 4096
#define HH2 4096

typedef __attribute__((ext_vector_type(8))) short bf16x8;
typedef __attribute__((ext_vector_type(4))) float f32x4;
typedef unsigned short ushort_t;

// ws layout (bytes):
//   [0)        vectors, 64 KB:
//     [0)     u0 (4096 f32)   -- overlaid by P (512 f32, k4 partials) after k0a
//     [16384) q  (4096 f32)
//     [32768) s  (4096 f32)
//     [49152) cv (4096 f32)
//   [65536)    A' = bf16(W2 .* s)  4096x4096 (33554432 B)
//   [33619968) B' = bf16(W1^T)     1024x4096 ( 8388608 B)
//   [42008576) cd (4096 f32, 16384 B) -- only if ws_size >= 42024960
#define WS_BASE_BYTES 42008576ull
#define WS_CD_BYTES   42024960ull

__device__ inline void wave_reduce2(float& a, float& b) {
  #pragma unroll
  for (int off = 32; off > 0; off >>= 1) {
    a += __shfl_down(a, off, 64);
    b += __shfl_down(b, off, 64);
  }
}

// fp32 -> bf16 RNE
__device__ inline unsigned int f2b(float f) {
  union { float f; unsigned int u; } v; v.f = f;
  return (v.u + 0x7FFFu + ((v.u >> 16) & 1u)) >> 16;
}
__device__ inline unsigned int pack2(float a, float b) {
  return f2b(a) | (f2b(b) << 16);
}

// async global->LDS, 16 B per lane; lds ptr = wave-uniform base + lane*16
__device__ inline void gl_lds16(const void* g, void* l) {
  __builtin_amdgcn_global_load_lds(
      (const __attribute__((address_space(1))) unsigned int*)g,
      (__attribute__((address_space(3))) unsigned int*)l, 16, 0, 0);
}

// K1: per-row h of W1: a0=W1[h,:]·x+b1, r=Σ W1[h,i]^2 → u0,s,q. Zeroes out.
__global__ __launch_bounds__(256) void k1_layer1(
    const float* __restrict__ W1, const float* __restrict__ x,
    const float* __restrict__ b1, float* __restrict__ u0,
    float* __restrict__ q, float* __restrict__ s_out,
    float* __restrict__ out) {
  int h = blockIdx.x;
  int tid = threadIdx.x;
  const float4* row = (const float4*)(W1 + (size_t)h * DD);
  const float4* x4 = (const float4*)x;
  float4 w = row[tid];
  float4 xv = x4[tid];
  float dot = w.x * xv.x + w.y * xv.y + w.z * xv.z + w.w * xv.w;
  float sq = w.x * w.x + w.y * w.y + w.z * w.z + w.w * w.w;
  wave_reduce2(dot, sq);
  __shared__ float lds[8];
  int lane = tid & 63, wid = tid >> 6;
  if (lane == 0) { lds[wid * 2] = dot; lds[wid * 2 + 1] = sq; }
  __syncthreads();
  if (tid == 0) {
    float dsum = lds[0] + lds[2] + lds[4] + lds[6];
    float rsum = lds[1] + lds[3] + lds[5] + lds[7];
    float a0 = dsum + b1[h];
    float u = tanhf(a0);
    float s = 1.f - u * u;
    u0[h] = u;
    s_out[h] = s;
    q[h] = -2.f * u * s * rsum;
    if (h == 0) out[0] = 0.f;
  }
}

// K0b: transpose-convert W1 [4096 h][1024 i] fp32 -> B' [1024 i][4096 h] bf16.
__global__ __launch_bounds__(256) void k0b_transpose(
    const float* __restrict__ W1, ushort_t* __restrict__ Bp) {
  __shared__ ushort_t T[64][72];
  int tid = threadIdx.x;
  int k0 = blockIdx.x * 64;
  int i0 = blockIdx.y * 64;
  int kr = tid >> 4;
  int ic = (tid & 15) * 4;
  #pragma unroll
  for (int p = 0; p < 4; ++p) {
    int k = kr + p * 16;
    float4 v = *(const float4*)(W1 + (size_t)(k0 + k) * DD + i0 + ic);
    T[ic + 0][k] = (ushort_t)f2b(v.x);
    T[ic + 1][k] = (ushort_t)f2b(v.y);
    T[ic + 2][k] = (ushort_t)f2b(v.z);
    T[ic + 3][k] = (ushort_t)f2b(v.w);
  }
  __syncthreads();
  int kc = tid & 7;
  int ir = tid >> 3;
  #pragma unroll
  for (int p = 0; p < 2; ++p) {
    int i = ir + p * 32;
    uint4 v = *(const uint4*)&T[i][kc * 8];
    *(uint4*)(Bp + (size_t)(i0 + i) * HH1 + k0 + kc * 8) = v;
  }
}

// K0a: per-row g of W2: z=W2[g,:]·u0+b2, d=W2[g,:]·q,
// A'[g,:]=bf16(W2[g,:].*s); cv[g]=c*v0; cd[g]=c*d (or atomic fallback).
__global__ __launch_bounds__(256) void k0a_layer2conv(
    const float* __restrict__ W2, const float* __restrict__ b2,
    const float* __restrict__ W3, const float* __restrict__ u0,
    const float* __restrict__ q, const float* __restrict__ s,
    ushort_t* __restrict__ Ap, float* __restrict__ cv,
    float* __restrict__ cd, int use_cd, float* __restrict__ out) {
  int g = blockIdx.x;
  int tid = threadIdx.x;
  const float4* row = (const float4*)(W2 + (size_t)g * HH1);
  const float4* u4 = (const float4*)u0;
  const float4* q4 = (const float4*)q;
  const float4* s4 = (const float4*)s;
  float zacc = 0.f, dacc = 0.f;
  #pragma unroll
  for (int it = 0; it < 4; ++it) {
    int j = tid + it * 256;
    float4 w = row[j];
    float4 u = u4[j];
    float4 qq = q4[j];
    float4 sv = s4[j];
    zacc += w.x * u.x + w.y * u.y + w.z * u.z + w.w * u.w;
    dacc += w.x * qq.x + w.y * qq.y + w.z * qq.z + w.w * qq.w;
    uint2 pk;
    pk.x = pack2(w.x * sv.x, w.y * sv.y);
    pk.y = pack2(w.z * sv.z, w.w * sv.w);
    *(uint2*)(Ap + (size_t)g * HH1 + j * 4) = pk;
  }
  wave_reduce2(zacc, dacc);
  __shared__ float lds[8];
  int lane = tid & 63, wid = tid >> 6;
  if (lane == 0) { lds[wid * 2] = zacc; lds[wid * 2 + 1] = dacc; }
  __syncthreads();
  if (tid == 0) {
    float z = lds[0] + lds[2] + lds[4] + lds[6] + b2[g];
    float d = lds[1] + lds[3] + lds[5] + lds[7];
    float v = tanhf(z);
    float t = 1.f - v * v;
    float c = W3[g] * t;
    cv[g] = c * v;
    if (use_cd) cd[g] = c * d;
    else atomicAdd(out, c * d);
  }
}

// K4: bf16 GEMM-BT M = A'·B'^T, tile 128(g) x 64(i), BK=64, gl_lds16 staging.
// LDS rows are 128 B = 8 x 16B chunks; logical chunk c lives at c^(row&7)
// (both staged and read that way) -> 2-way banks (free), b128 frag reads.
// Epilogue: P[block] = Σ cv[g]*M[g,i]^2 over this tile. No atomics.
__global__ __launch_bounds__(256) void k4_bt64(
    const ushort_t* __restrict__ Ap, const ushort_t* __restrict__ Bp,
    const float* __restrict__ cv, float* __restrict__ P) {
  __shared__ __align__(16) ushort_t As[128][64];
  __shared__ __align__(16) ushort_t Bs[64][64];
  __shared__ float red[4];
  const int tid = threadIdx.x;
  const int lane = tid & 63;
  const int wave = tid >> 6;
  const int wm = wave >> 1, wn = wave & 1;
  // XCD swizzle: XCD c owns g-stripes {4c..4c+3} x all i
  const int l = blockIdx.x;
  const int xcd = l & 7, j = l >> 3;
  const int g0 = (xcd * 4 + (j & 3)) * 128;
  const int i0 = (j >> 2) * 64;

  const int srow = lane >> 3;   // 0..7 row within an 8-row staging group
  const int schk = lane & 7;    // physical 16B chunk this lane fills

  f32x4 acc[4][2];
  const f32x4 zero = {0.f, 0.f, 0.f, 0.f};
  #pragma unroll
  for (int mt = 0; mt < 4; ++mt)
    #pragma unroll
    for (int nt = 0; nt < 2; ++nt) acc[mt][nt] = zero;

  const int fr = lane & 15;
  const int fc = lane >> 4;

  for (int ko = 0; ko < HH1 / 64; ++ko) {
    const int k0 = ko * 64;
    // stage A: wave w covers rows [w*32, w*32+32), 4 calls x 8 rows
    #pragma unroll
    for (int p = 0; p < 4; ++p) {
      int row = wave * 32 + p * 8 + srow;
      int lc = schk ^ (row & 7);
      gl_lds16(Ap + (size_t)(g0 + row) * HH1 + k0 + lc * 8,
               (char*)&As[0][0] + (wave * 32 + p * 8) * 128 + lane * 16);
    }
    // stage B: wave w covers rows [w*16, w*16+16), 2 calls x 8 rows
    #pragma unroll
    for (int p = 0; p < 2; ++p) {
      int row = wave * 16 + p * 8 + srow;
      int lc = schk ^ (row & 7);
      gl_lds16(Bp + (size_t)(i0 + row) * HH1 + k0 + lc * 8,
               (char*)&Bs[0][0] + (wave * 16 + p * 8) * 128 + lane * 16);
    }
    __syncthreads();  // drains vmcnt (global_load_lds)
    bf16x8 af[2][4], bfv[2][2];
    #pragma unroll
    for (int kk = 0; kk < 2; ++kk) {
      #pragma unroll
      for (int mt = 0; mt < 4; ++mt) {
        int row = wm * 64 + mt * 16 + fr;
        af[kk][mt] = *(const bf16x8*)&As[row][((kk * 4 + fc) ^ (row & 7)) * 8];
      }
      #pragma unroll
      for (int nt = 0; nt < 2; ++nt) {
        int row = wn * 32 + nt * 16 + fr;
        bfv[kk][nt] = *(const bf16x8*)&Bs[row][((kk * 4 + fc) ^ (row & 7)) * 8];
      }
    }
    #pragma unroll
    for (int kk = 0; kk < 2; ++kk)
      #pragma unroll
      for (int mt = 0; mt < 4; ++mt)
        #pragma unroll
        for (int nt = 0; nt < 2; ++nt)
          acc[mt][nt] = __builtin_amdgcn_mfma_f32_16x16x32_bf16(
              af[kk][mt], bfv[kk][nt], acc[mt][nt], 0, 0, 0);
    __syncthreads();
  }

  float part = 0.f;
  #pragma unroll
  for (int mt = 0; mt < 4; ++mt) {
    #pragma unroll
    for (int r = 0; r < 4; ++r) {
      int g = g0 + wm * 64 + mt * 16 + fc * 4 + r;
      float c = cv[g];
      float ss = 0.f;
      #pragma unroll
      for (int nt = 0; nt < 2; ++nt) {
        float v = acc[mt][nt][r];
        ss += v * v;
      }
      part += c * ss;
    }
  }
  #pragma unroll
  for (int off = 32; off > 0; off >>= 1) part += __shfl_down(part, off, 64);
  if (lane == 0) red[wave] = part;
  __syncthreads();
  if (tid == 0) P[l] = red[0] + red[1] + red[2] + red[3];
}

// K5: out[0] += Σ cd (if use_cd) - 2 Σ P.  Single block.
__global__ __launch_bounds__(256) void k5_final(
    const float* __restrict__ cd, const float* __restrict__ P,
    int use_cd, float* __restrict__ out) {
  int tid = threadIdx.x;
  float a = 0.f, b = 0.f;
  if (use_cd)
    for (int j = tid; j < HH2; j += 256) a += cd[j];
  for (int j = tid; j < 512; j += 256) b += P[j];
  float v = a - 2.f * b;
  #pragma unroll
  for (int off = 32; off > 0; off >>= 1) v += __shfl_down(v, off, 64);
  __shared__ float lds[4];
  int lane = tid & 63, wid = tid >> 6;
  if (lane == 0) lds[wid] = v;
  __syncthreads();
  if (tid == 0) out[0] = out[0] + lds[0] + lds[1] + lds[2] + lds[3];
}

extern "C" void kernel_launch(void* const* d_in, const int* in_sizes, int n_in,
                              void* d_out, int out_size, void* d_ws, size_t ws_size,
                              hipStream_t stream) {
  const float* x  = (const float*)d_in[0];
  const float* W1 = (const float*)d_in[1];
  const float* b1 = (const float*)d_in[2];
  const float* W2 = (const float*)d_in[3];
  const float* b2 = (const float*)d_in[4];
  const float* W3 = (const float*)d_in[5];
  float* out = (float*)d_out;
  float* ws = (float*)d_ws;
  float* u0 = ws;               // overlaid by P after k0a completes
  float* q  = ws + 4096;
  float* s  = ws + 8192;
  float* cv = ws + 12288;
  float* P  = ws;               // 512 floats, k4 -> k5
  ushort_t* Ap = (ushort_t*)((char*)d_ws + 65536);
  ushort_t* Bp = (ushort_t*)((char*)d_ws + 33619968);
  int use_cd = (ws_size >= WS_CD_BYTES) ? 1 : 0;
  float* cd = (float*)((char*)d_ws + WS_BASE_BYTES);

  hipLaunchKernelGGL(k1_layer1, dim3(HH1), dim3(256), 0, stream,
                     W1, x, b1, u0, q, s, out);
  hipLaunchKernelGGL(k0b_transpose, dim3(64, 16), dim3(256), 0, stream, W1, Bp);
  hipLaunchKernelGGL(k0a_layer2conv, dim3(HH2), dim3(256), 0, stream,
                     W2, b2, W3, u0, q, s, Ap, cv, cd, use_cd, out);
  hipLaunchKernelGGL(k4_bt64, dim3(512), dim3(256), 0, stream, Ap, Bp, cv, P);
  hipLaunchKernelGGL(k5_final, dim3(1), dim3(256), 0, stream, cd, P, use_cd, out);
}

// Round 5
// 181.969 us; speedup vs baseline: 3.7462x; 1.0610x over previous
//
#include <hip/hip_runtime.h>
#include <math.h>

#define DD 1024
#define HH1 4096
#define HH2 4096

typedef __attribute__((ext_vector_type(8))) short bf16x8;
typedef __attribute__((ext_vector_type(4))) float f32x4;
typedef unsigned short ushort_t;

// fast-path ws layout (bytes) — total exactly 42,008,576 (proven available R3/R4):
//   [0)        u0 (4096 f32)   -- overlaid by P (512 f32) after k0a
//   [16384)    q  (4096 f32)
//   [32768)    cv (4096 f32)
//   [49152)    cd (4096 f32)
//   [65536)    A' = bf16(W2 .* s)  4096x4096 (33554432 B)
//   [33619968) B' = bf16(W1^T)     1024x4096 ( 8388608 B)
#define WS_FAST_BYTES 42008576ull

__device__ inline void wave_reduce2(float& a, float& b) {
  #pragma unroll
  for (int off = 32; off > 0; off >>= 1) {
    a += __shfl_down(a, off, 64);
    b += __shfl_down(b, off, 64);
  }
}

// fp32 -> bf16 RNE
__device__ inline unsigned int f2b(float f) {
  union { float f; unsigned int u; } v; v.f = f;
  return (v.u + 0x7FFFu + ((v.u >> 16) & 1u)) >> 16;
}
__device__ inline unsigned int pack2(float a, float b) {
  return f2b(a) | (f2b(b) << 16);
}

// async global->LDS, 16 B per lane; lds dst = wave-uniform base + lane*16
__device__ inline void gl_lds16(const void* g, void* l) {
  __builtin_amdgcn_global_load_lds(
      (const __attribute__((address_space(1))) unsigned int*)g,
      (__attribute__((address_space(3))) unsigned int*)l, 16, 0, 0);
}

// kA: fused layer-1 + W1 transpose-convert. Block = 8 rows of W1.
// Per row h: a0=W1[h,:]·x+b1 -> u0[h], q[h]=-2*u*s*ΣW1[h,i]^2.
// Also emits B'[i][h] = bf16(W1[h][i]) via LDS transpose.
__global__ __launch_bounds__(256) void kA_l1t(
    const float* __restrict__ W1, const float* __restrict__ x,
    const float* __restrict__ b1, float* __restrict__ u0,
    float* __restrict__ q, ushort_t* __restrict__ Bp) {
  __shared__ ushort_t T[8][1032];  // +8 pad
  const int tid = threadIdx.x, lane = tid & 63, w = tid >> 6;
  const int h0 = blockIdx.x * 8;
  const float4* x4 = (const float4*)x;
  #pragma unroll
  for (int rr = 0; rr < 2; ++rr) {
    int row = w * 2 + rr;  // 0..7
    const float4* rp = (const float4*)(W1 + (size_t)(h0 + row) * DD);
    float dot = 0.f, sq = 0.f;
    #pragma unroll
    for (int j = 0; j < 4; ++j) {
      int idx = j * 64 + lane;
      float4 wv = rp[idx];
      float4 xv = x4[idx];
      dot += wv.x * xv.x + wv.y * xv.y + wv.z * xv.z + wv.w * xv.w;
      sq  += wv.x * wv.x + wv.y * wv.y + wv.z * wv.z + wv.w * wv.w;
      uint2 pk;
      pk.x = pack2(wv.x, wv.y);
      pk.y = pack2(wv.z, wv.w);
      *(uint2*)&T[row][idx * 4] = pk;
    }
    wave_reduce2(dot, sq);
    if (lane == 0) {
      float a0 = dot + b1[h0 + row];
      float u = tanhf(a0);
      float s = 1.f - u * u;
      u0[h0 + row] = u;
      q[h0 + row] = -2.f * u * s * sq;
    }
  }
  __syncthreads();
  #pragma unroll
  for (int j = 0; j < 4; ++j) {
    int i = j * 256 + tid;
    union { uint4 v; ushort_t us[8]; } pk;
    #pragma unroll
    for (int h = 0; h < 8; ++h) pk.us[h] = T[h][i];
    *(uint4*)(Bp + (size_t)i * HH1 + h0) = pk.v;  // h0*2 B = 16B-aligned
  }
}

// k0a: per-row g of W2: z=W2[g,:]·u0+b2, d=W2[g,:]·q; s recomputed as 1-u0^2
// (bit-identical to stored-s path). A'[g,:]=bf16(W2[g,:].*s); cv[g]=c*v0; cd[g]=c*d.
__global__ __launch_bounds__(256) void k0a_layer2conv(
    const float* __restrict__ W2, const float* __restrict__ b2,
    const float* __restrict__ W3, const float* __restrict__ u0,
    const float* __restrict__ q, ushort_t* __restrict__ Ap,
    float* __restrict__ cv, float* __restrict__ cd) {
  int g = blockIdx.x;
  int tid = threadIdx.x;
  const float4* row = (const float4*)(W2 + (size_t)g * HH1);
  const float4* u4 = (const float4*)u0;
  const float4* q4 = (const float4*)q;
  float zacc = 0.f, dacc = 0.f;
  #pragma unroll
  for (int it = 0; it < 4; ++it) {
    int j = tid + it * 256;
    float4 w = row[j];
    float4 u = u4[j];
    float4 qq = q4[j];
    float4 sv;
    sv.x = 1.f - u.x * u.x;
    sv.y = 1.f - u.y * u.y;
    sv.z = 1.f - u.z * u.z;
    sv.w = 1.f - u.w * u.w;
    zacc += w.x * u.x + w.y * u.y + w.z * u.z + w.w * u.w;
    dacc += w.x * qq.x + w.y * qq.y + w.z * qq.z + w.w * qq.w;
    uint2 pk;
    pk.x = pack2(w.x * sv.x, w.y * sv.y);
    pk.y = pack2(w.z * sv.z, w.w * sv.w);
    *(uint2*)(Ap + (size_t)g * HH1 + j * 4) = pk;
  }
  wave_reduce2(zacc, dacc);
  __shared__ float lds[8];
  int lane = tid & 63, wid = tid >> 6;
  if (lane == 0) { lds[wid * 2] = zacc; lds[wid * 2 + 1] = dacc; }
  __syncthreads();
  if (tid == 0) {
    float z = lds[0] + lds[2] + lds[4] + lds[6] + b2[g];
    float d = lds[1] + lds[3] + lds[5] + lds[7];
    float v = tanhf(z);
    float t = 1.f - v * v;
    float c = W3[g] * t;
    cv[g] = c * v;
    cd[g] = c * d;
  }
}

// k4: bf16 GEMM-BT M = A'·B'^T, tile 128(g) x 64(i), BK=128, gl_lds16 staging.
// LDS rows 256 B = 16 x 16B chunks; logical chunk c stored at c^(row&15).
// 32 MFMA per barrier-pair, 32 K-iters. Epilogue: P[block]=Σ cv[g]*M[g,i]^2.
__global__ __launch_bounds__(256) void k4_bt128(
    const ushort_t* __restrict__ Ap, const ushort_t* __restrict__ Bp,
    const float* __restrict__ cv, float* __restrict__ P) {
  __shared__ __align__(16) ushort_t As[128][128];
  __shared__ __align__(16) ushort_t Bs[64][128];
  __shared__ float red[4];
  const int tid = threadIdx.x;
  const int lane = tid & 63;
  const int wave = tid >> 6;
  const int wm = wave >> 1, wn = wave & 1;
  // XCD swizzle: XCD c owns g-stripes {4c..4c+3} x all i
  const int l = blockIdx.x;
  const int xcd = l & 7, j = l >> 3;
  const int g0 = (xcd * 4 + (j & 3)) * 128;
  const int i0 = (j >> 2) * 64;

  const int srow = lane >> 4;   // 0..3 row within a 4-row staging call
  const int schk = lane & 15;   // physical 16B chunk this lane fills

  f32x4 acc[4][2];
  const f32x4 zero = {0.f, 0.f, 0.f, 0.f};
  #pragma unroll
  for (int mt = 0; mt < 4; ++mt)
    #pragma unroll
    for (int nt = 0; nt < 2; ++nt) acc[mt][nt] = zero;

  const int fr = lane & 15;
  const int fc = lane >> 4;

  for (int ko = 0; ko < HH1 / 128; ++ko) {
    const int k0 = ko * 128;
    // stage A: wave w covers rows [w*32, w*32+32), 8 calls x 4 rows
    #pragma unroll
    for (int p = 0; p < 8; ++p) {
      int row = wave * 32 + p * 4 + srow;
      int lc = schk ^ (row & 15);
      gl_lds16(Ap + (size_t)(g0 + row) * HH1 + k0 + lc * 8,
               (char*)&As[0][0] + (wave * 32 + p * 4) * 256 + lane * 16);
    }
    // stage B: wave w covers rows [w*16, w*16+16), 4 calls x 4 rows
    #pragma unroll
    for (int p = 0; p < 4; ++p) {
      int row = wave * 16 + p * 4 + srow;
      int lc = schk ^ (row & 15);
      gl_lds16(Bp + (size_t)(i0 + row) * HH1 + k0 + lc * 8,
               (char*)&Bs[0][0] + (wave * 16 + p * 4) * 256 + lane * 16);
    }
    __syncthreads();  // drains vmcnt (global_load_lds)
    #pragma unroll
    for (int kk = 0; kk < 4; ++kk) {
      bf16x8 af[4], bfv[2];
      #pragma unroll
      for (int mt = 0; mt < 4; ++mt) {
        int row = wm * 64 + mt * 16 + fr;
        af[mt] = *(const bf16x8*)&As[row][((kk * 4 + fc) ^ (row & 15)) * 8];
      }
      #pragma unroll
      for (int nt = 0; nt < 2; ++nt) {
        int row = wn * 32 + nt * 16 + fr;
        bfv[nt] = *(const bf16x8*)&Bs[row][((kk * 4 + fc) ^ (row & 15)) * 8];
      }
      #pragma unroll
      for (int mt = 0; mt < 4; ++mt)
        #pragma unroll
        for (int nt = 0; nt < 2; ++nt)
          acc[mt][nt] = __builtin_amdgcn_mfma_f32_16x16x32_bf16(
              af[mt], bfv[nt], acc[mt][nt], 0, 0, 0);
    }
    __syncthreads();
  }

  float part = 0.f;
  #pragma unroll
  for (int mt = 0; mt < 4; ++mt) {
    #pragma unroll
    for (int r = 0; r < 4; ++r) {
      int g = g0 + wm * 64 + mt * 16 + fc * 4 + r;
      float c = cv[g];
      float ss = 0.f;
      #pragma unroll
      for (int nt = 0; nt < 2; ++nt) {
        float v = acc[mt][nt][r];
        ss += v * v;
      }
      part += c * ss;
    }
  }
  #pragma unroll
  for (int off = 32; off > 0; off >>= 1) part += __shfl_down(part, off, 64);
  if (lane == 0) red[wave] = part;
  __syncthreads();
  if (tid == 0) P[l] = red[0] + red[1] + red[2] + red[3];
}

// k5: out[0] = Σ cd - 2 Σ P. Plain store (no atomics, no zero-init needed).
__global__ __launch_bounds__(256) void k5_final(
    const float* __restrict__ cd, const float* __restrict__ P,
    float* __restrict__ out) {
  int tid = threadIdx.x;
  float a = 0.f, b = 0.f;
  for (int j = tid; j < HH2; j += 256) a += cd[j];
  for (int j = tid; j < 512; j += 256) b += P[j];
  float v = a - 2.f * b;
  #pragma unroll
  for (int off = 32; off > 0; off >>= 1) v += __shfl_down(v, off, 64);
  __shared__ float lds[4];
  int lane = tid & 63, wid = tid >> 6;
  if (lane == 0) lds[wid] = v;
  __syncthreads();
  if (tid == 0) out[0] = lds[0] + lds[1] + lds[2] + lds[3];
}

// ---------------- fallback (fp32, ws = 64 KB only; R1-proven) ----------------

__global__ __launch_bounds__(256) void k1_slow(
    const float* __restrict__ W1, const float* __restrict__ x,
    const float* __restrict__ b1, float* __restrict__ u0,
    float* __restrict__ q, float* __restrict__ s_out,
    float* __restrict__ out) {
  int h = blockIdx.x;
  int tid = threadIdx.x;
  const float4* row = (const float4*)(W1 + (size_t)h * DD);
  const float4* x4 = (const float4*)x;
  float4 w = row[tid];
  float4 xv = x4[tid];
  float dot = w.x * xv.x + w.y * xv.y + w.z * xv.z + w.w * xv.w;
  float sq = w.x * w.x + w.y * w.y + w.z * w.z + w.w * w.w;
  wave_reduce2(dot, sq);
  __shared__ float lds[8];
  int lane = tid & 63, wid = tid >> 6;
  if (lane == 0) { lds[wid * 2] = dot; lds[wid * 2 + 1] = sq; }
  __syncthreads();
  if (tid == 0) {
    float dsum = lds[0] + lds[2] + lds[4] + lds[6];
    float rsum = lds[1] + lds[3] + lds[5] + lds[7];
    float a0 = dsum + b1[h];
    float u = tanhf(a0);
    float s = 1.f - u * u;
    u0[h] = u;
    s_out[h] = s;
    q[h] = -2.f * u * s * rsum;
    if (h == 0) out[0] = 0.f;
  }
}

__global__ __launch_bounds__(256) void k2_slow(
    const float* __restrict__ W2, const float* __restrict__ b2,
    const float* __restrict__ W3, const float* __restrict__ u0,
    const float* __restrict__ q, float* __restrict__ cv,
    float* __restrict__ out) {
  int g = blockIdx.x;
  int tid = threadIdx.x;
  const float4* row = (const float4*)(W2 + (size_t)g * HH1);
  const float4* u4 = (const float4*)u0;
  const float4* q4 = (const float4*)q;
  float zacc = 0.f, dacc = 0.f;
  for (int j = tid; j < HH1 / 4; j += 256) {
    float4 w = row[j];
    float4 u = u4[j];
    float4 qq = q4[j];
    zacc += w.x * u.x + w.y * u.y + w.z * u.z + w.w * u.w;
    dacc += w.x * qq.x + w.y * qq.y + w.z * qq.z + w.w * qq.w;
  }
  wave_reduce2(zacc, dacc);
  __shared__ float lds[8];
  int lane = tid & 63, wid = tid >> 6;
  if (lane == 0) { lds[wid * 2] = zacc; lds[wid * 2 + 1] = dacc; }
  __syncthreads();
  if (tid == 0) {
    float z = lds[0] + lds[2] + lds[4] + lds[6] + b2[g];
    float d = lds[1] + lds[3] + lds[5] + lds[7];
    float v = tanhf(z);
    float t = 1.f - v * v;
    float c = W3[g] * t;
    cv[g] = c * v;
    atomicAdd(out, c * d);
  }
}

__global__ __launch_bounds__(256) void k4_slow(
    const float* __restrict__ W2, const float* __restrict__ W1,
    const float* __restrict__ s, const float* __restrict__ cv,
    float* __restrict__ out) {
  __shared__ float As[32][68];
  __shared__ float Bs[32][68];
  int tid = threadIdx.x;
  int g0 = blockIdx.y * 64;
  int i0 = blockIdx.x * 64;
  int tr = (tid / 16) * 4;
  int tc = (tid % 16) * 4;
  float acc[4][4] = {};
  for (int k0 = 0; k0 < HH1; k0 += 32) {
    for (int ll = tid; ll < (64 * 32 / 4); ll += 256) {
      int row = ll / 8;
      int c4 = ll % 8;
      float4 w = *(const float4*)(W2 + (size_t)(g0 + row) * HH1 + k0 + c4 * 4);
      float4 sv = *(const float4*)(s + k0 + c4 * 4);
      As[c4 * 4 + 0][row] = w.x * sv.x;
      As[c4 * 4 + 1][row] = w.y * sv.y;
      As[c4 * 4 + 2][row] = w.z * sv.z;
      As[c4 * 4 + 3][row] = w.w * sv.w;
    }
    for (int ll = tid; ll < (32 * 64 / 4); ll += 256) {
      int row = ll / 16;
      int c4 = ll % 16;
      float4 w = *(const float4*)(W1 + (size_t)(k0 + row) * DD + i0 + c4 * 4);
      *(float4*)&Bs[row][c4 * 4] = w;
    }
    __syncthreads();
    #pragma unroll
    for (int k = 0; k < 32; ++k) {
      float4 av = *(const float4*)&As[k][tr];
      float4 bv = *(const float4*)&Bs[k][tc];
      float a_[4] = {av.x, av.y, av.z, av.w};
      float b_[4] = {bv.x, bv.y, bv.z, bv.w};
      #pragma unroll
      for (int r = 0; r < 4; ++r)
        #pragma unroll
        for (int c = 0; c < 4; ++c)
          acc[r][c] += a_[r] * b_[c];
    }
    __syncthreads();
  }
  float contrib = 0.f;
  #pragma unroll
  for (int r = 0; r < 4; ++r) {
    float ss = acc[r][0] * acc[r][0] + acc[r][1] * acc[r][1] +
               acc[r][2] * acc[r][2] + acc[r][3] * acc[r][3];
    contrib += cv[g0 + tr + r] * ss;
  }
  #pragma unroll
  for (int off = 32; off > 0; off >>= 1) contrib += __shfl_down(contrib, off, 64);
  __shared__ float red[4];
  int lane = tid & 63, wid = tid >> 6;
  if (lane == 0) red[wid] = contrib;
  __syncthreads();
  if (tid == 0) atomicAdd(out, -2.f * (red[0] + red[1] + red[2] + red[3]));
}

extern "C" void kernel_launch(void* const* d_in, const int* in_sizes, int n_in,
                              void* d_out, int out_size, void* d_ws, size_t ws_size,
                              hipStream_t stream) {
  const float* x  = (const float*)d_in[0];
  const float* W1 = (const float*)d_in[1];
  const float* b1 = (const float*)d_in[2];
  const float* W2 = (const float*)d_in[3];
  const float* b2 = (const float*)d_in[4];
  const float* W3 = (const float*)d_in[5];
  // b3 (d_in[6]) vanishes under the Laplacian.
  float* out = (float*)d_out;
  float* ws = (float*)d_ws;

  if (ws_size >= WS_FAST_BYTES) {
    float* u0 = ws;              // overlaid by P after k0a completes
    float* q  = ws + 4096;
    float* cv = ws + 8192;
    float* cd = ws + 12288;
    float* P  = ws;              // 512 floats, k4 -> k5
    ushort_t* Ap = (ushort_t*)((char*)d_ws + 65536);
    ushort_t* Bp = (ushort_t*)((char*)d_ws + 33619968);
    hipLaunchKernelGGL(kA_l1t, dim3(512), dim3(256), 0, stream,
                       W1, x, b1, u0, q, Bp);
    hipLaunchKernelGGL(k0a_layer2conv, dim3(HH2), dim3(256), 0, stream,
                       W2, b2, W3, u0, q, Ap, cv, cd);
    hipLaunchKernelGGL(k4_bt128, dim3(512), dim3(256), 0, stream, Ap, Bp, cv, P);
    hipLaunchKernelGGL(k5_final, dim3(1), dim3(256), 0, stream, cd, P, out);
  } else {
    float* u0 = ws;
    float* q  = ws + 4096;
    float* s  = ws + 8192;
    float* cv = ws + 12288;
    hipLaunchKernelGGL(k1_slow, dim3(HH1), dim3(256), 0, stream,
                       W1, x, b1, u0, q, s, out);
    hipLaunchKernelGGL(k2_slow, dim3(HH2), dim3(256), 0, stream,
                       W2, b2, W3, u0, q, cv, out);
    hipLaunchKernelGGL(k4_slow, dim3(DD / 64, HH2 / 64), dim3(256), 0, stream,
                       W2, W1, s, cv, out);
  }
}